// Round 6
// baseline (326.833 us; speedup 1.0000x reference)
//
#include <hip/hip_runtime.h>
#include <hip/hip_fp16.h>
#include <math.h>

#define N_NODES 50000
#define N_EDGES 800000
#define IN_FEATS 128
#define N_HIDDEN 64
#define OUT_FEATS 40
#define DIM 8
#define SCAN_NB ((N_NODES + 255) / 256)   // 196

// ---------------- wave-wide inclusive scan (64 lanes) ----------------
__device__ __forceinline__ int wave_incl_scan(int x, int lane) {
#pragma unroll
    for (int off = 1; off < 64; off <<= 1) {
        int v = __shfl_up(x, off, 64);
        if (lane >= off) x += v;
    }
    return x;
}

// ---------------- CSR build: in-degree histogram ----------------
__global__ void hist_kernel(const int* __restrict__ dst, int* __restrict__ counts) {
    int e = blockIdx.x * blockDim.x + threadIdx.x;
    if (e < N_EDGES) atomicAdd(&counts[dst[e]], 1);
}

// ---------------- scan phase 1 ----------------
__global__ __launch_bounds__(256) void scan_blk_kernel(const int* __restrict__ counts,
                                                       int* __restrict__ offsets,
                                                       int* __restrict__ blkSums) {
    int i = blockIdx.x * 256 + threadIdx.x;
    int lane = threadIdx.x & 63, wid = threadIdx.x >> 6;
    int x = (i < N_NODES) ? counts[i] : 0;
    int incl = wave_incl_scan(x, lane);
    __shared__ int wsum[4];
    if (lane == 63) wsum[wid] = incl;
    __syncthreads();
    int base = 0;
#pragma unroll
    for (int w = 0; w < 4; ++w)
        if (w < wid) base += wsum[w];
    if (i < N_NODES) offsets[i] = base + incl - x;
    if (threadIdx.x == 255) blkSums[blockIdx.x] = base + incl;
}

// ---------------- scan phase 2 ----------------
__global__ __launch_bounds__(256) void scan_top_kernel(int* __restrict__ blkSums) {
    int i = threadIdx.x;
    int lane = i & 63, wid = i >> 6;
    int x = (i < SCAN_NB) ? blkSums[i] : 0;
    int incl = wave_incl_scan(x, lane);
    __shared__ int wsum[4];
    if (lane == 63) wsum[wid] = incl;
    __syncthreads();
    int base = 0;
#pragma unroll
    for (int w = 0; w < 4; ++w)
        if (w < wid) base += wsum[w];
    if (i < SCAN_NB) blkSums[i] = base + incl - x;
}

// ---------------- scan phase 3 ----------------
__global__ __launch_bounds__(256) void scan_add_kernel(int* __restrict__ offsets,
                                                       const int* __restrict__ blkSums,
                                                       int* __restrict__ cursor) {
    int i = blockIdx.x * 256 + threadIdx.x;
    if (i < N_NODES) {
        int v = offsets[i] + blkSums[blockIdx.x];
        offsets[i] = v;
        cursor[i]  = v;
    }
    if (blockIdx.x == 0 && threadIdx.x == 0)
        offsets[N_NODES] = N_EDGES;
}

// ---------------- CSR fill: ONE 8B store per edge {src:int, (g1,g2):half2} ----------------
__global__ void fill_kernel(const int* __restrict__ src, const int* __restrict__ dst,
                            const float* __restrict__ ew,
                            const float* __restrict__ mu1, const float* __restrict__ is1,
                            const float* __restrict__ mu2, const float* __restrict__ is2,
                            int* __restrict__ cursor,
                            int2* __restrict__ csr) {
    int e = blockIdx.x * blockDim.x + threadIdx.x;
    if (e >= N_EDGES) return;
    float s1 = 0.f, s2 = 0.f;
#pragma unroll
    for (int d = 0; d < DIM; ++d) {
        float v = ew[e * DIM + d];
        float d1 = v - mu1[d]; float a1 = is1[d];
        float d2 = v - mu2[d]; float a2 = is2[d];
        s1 += d1 * d1 * a1 * a1;
        s2 += d2 * d2 * a2 * a2;
    }
    int pos = atomicAdd(&cursor[dst[e]], 1);
    __half2 g = __floats2half2_rn(expf(-0.5f * s1), expf(-0.5f * s2));
    int2 rec;
    rec.x = src[e];
    rec.y = *reinterpret_cast<int*>(&g);
    csr[pos] = rec;
}

// ---------------- h1 = features @ W1  -> fp16  [N,128]x[128,64] ----------------
// 256 threads = 4 waves; wave = 4 nodes; lane = ns*16 + f4 (4 output feats per lane)
__global__ __launch_bounds__(256) void gemm1_kernel(const float* __restrict__ x,
                                                    const float* __restrict__ W,
                                                    __half* __restrict__ h) {
    __shared__ float xs[4][4][132];
    int wid = threadIdx.x >> 6, lane = threadIdx.x & 63;
    int ns = lane >> 4, f4 = lane & 15;
    int nodeBase = blockIdx.x * 16 + wid * 4;
#pragma unroll
    for (int i = 0; i < 8; ++i) {
        int idx = lane + i * 64;
        int nn = idx >> 7, k = idx & 127;
        xs[wid][nn][k] = x[(size_t)(nodeBase + nn) * IN_FEATS + k];
    }
    const float4* W4 = (const float4*)W;
    float4 acc = make_float4(0.f, 0.f, 0.f, 0.f);
#pragma unroll 4
    for (int k = 0; k < IN_FEATS; ++k) {
        float xv = xs[wid][ns][k];
        float4 w = W4[k * 16 + f4];
        acc.x += xv * w.x; acc.y += xv * w.y;
        acc.z += xv * w.z; acc.w += xv * w.w;
    }
    int n = nodeBase + ns;
    __half2 lo = __floats2half2_rn(acc.x, acc.y);
    __half2 hi = __floats2half2_rn(acc.z, acc.w);
    uint2 pk;
    pk.x = *reinterpret_cast<unsigned*>(&lo);
    pk.y = *reinterpret_cast<unsigned*>(&hi);
    *reinterpret_cast<uint2*>(&h[(size_t)n * N_HIDDEN + 4 * f4]) = pk;
}

// ---------------- agg1 + gemm2 fused: h2[n] = (sum g1*h1[src] + b1) @ W2 -> fp16 ----------------
__global__ __launch_bounds__(256) void agg1_gemm2_kernel(const __half* __restrict__ h,
                                                         const int* __restrict__ offsets,
                                                         const int2* __restrict__ csr,
                                                         const float* __restrict__ b,
                                                         const float* __restrict__ W2,
                                                         __half* __restrict__ h2) {
    __shared__ float xs[4 * N_HIDDEN];
    int wid = threadIdx.x >> 6;
    int t   = threadIdx.x & 63;
    int n   = blockIdx.x * 4 + wid;
    int beg = offsets[n], end = offsets[n + 1];

    float a0 = 0.f, a1 = 0.f, a2 = 0.f, a3 = 0.f;
    int j = beg;
    for (; j + 8 <= end; j += 8) {
        int2 c0 = csr[j + 0], c1 = csr[j + 1], c2 = csr[j + 2], c3 = csr[j + 3];
        int2 c4 = csr[j + 4], c5 = csr[j + 5], c6 = csr[j + 6], c7 = csr[j + 7];
        float v0 = __half2float(h[(size_t)c0.x * N_HIDDEN + t]);
        float v1 = __half2float(h[(size_t)c1.x * N_HIDDEN + t]);
        float v2 = __half2float(h[(size_t)c2.x * N_HIDDEN + t]);
        float v3 = __half2float(h[(size_t)c3.x * N_HIDDEN + t]);
        float v4 = __half2float(h[(size_t)c4.x * N_HIDDEN + t]);
        float v5 = __half2float(h[(size_t)c5.x * N_HIDDEN + t]);
        float v6 = __half2float(h[(size_t)c6.x * N_HIDDEN + t]);
        float v7 = __half2float(h[(size_t)c7.x * N_HIDDEN + t]);
        a0 += v0 * __low2float(*reinterpret_cast<__half2*>(&c0.y));
        a1 += v1 * __low2float(*reinterpret_cast<__half2*>(&c1.y));
        a2 += v2 * __low2float(*reinterpret_cast<__half2*>(&c2.y));
        a3 += v3 * __low2float(*reinterpret_cast<__half2*>(&c3.y));
        a0 += v4 * __low2float(*reinterpret_cast<__half2*>(&c4.y));
        a1 += v5 * __low2float(*reinterpret_cast<__half2*>(&c5.y));
        a2 += v6 * __low2float(*reinterpret_cast<__half2*>(&c6.y));
        a3 += v7 * __low2float(*reinterpret_cast<__half2*>(&c7.y));
    }
    for (; j < end; ++j) {
        int2 c = csr[j];
        a0 += __half2float(h[(size_t)c.x * N_HIDDEN + t]) *
              __low2float(*reinterpret_cast<__half2*>(&c.y));
    }
    float x = (a0 + a1) + (a2 + a3) + b[t];

    xs[wid * N_HIDDEN + t] = x;   // wave-private region: no barrier needed
    if (t < OUT_FEATS) {
        const float* xr = &xs[wid * N_HIDDEN];
        float acc = 0.f;
#pragma unroll
        for (int k = 0; k < N_HIDDEN; ++k)
            acc += xr[k] * W2[k * OUT_FEATS + t];
        h2[(size_t)n * OUT_FEATS + t] = __float2half(acc);
    }
}

// ---------------- agg layer 2 + b2 + log_softmax fused ----------------
__global__ __launch_bounds__(256) void agg2_kernel(const __half* __restrict__ h,
                                                   const int* __restrict__ offsets,
                                                   const int2* __restrict__ csr,
                                                   const float* __restrict__ b,
                                                   float* __restrict__ out) {
    int n = blockIdx.x * 4 + (threadIdx.x >> 6);
    int t = threadIdx.x & 63;
    if (n >= N_NODES) return;
    int tc = (t < OUT_FEATS) ? t : (OUT_FEATS - 1);
    int beg = offsets[n], end = offsets[n + 1];
    float a0 = 0.f, a1 = 0.f, a2 = 0.f, a3 = 0.f;
    int j = beg;
    for (; j + 8 <= end; j += 8) {
        int2 c0 = csr[j + 0], c1 = csr[j + 1], c2 = csr[j + 2], c3 = csr[j + 3];
        int2 c4 = csr[j + 4], c5 = csr[j + 5], c6 = csr[j + 6], c7 = csr[j + 7];
        float v0 = __half2float(h[(size_t)c0.x * OUT_FEATS + tc]);
        float v1 = __half2float(h[(size_t)c1.x * OUT_FEATS + tc]);
        float v2 = __half2float(h[(size_t)c2.x * OUT_FEATS + tc]);
        float v3 = __half2float(h[(size_t)c3.x * OUT_FEATS + tc]);
        float v4 = __half2float(h[(size_t)c4.x * OUT_FEATS + tc]);
        float v5 = __half2float(h[(size_t)c5.x * OUT_FEATS + tc]);
        float v6 = __half2float(h[(size_t)c6.x * OUT_FEATS + tc]);
        float v7 = __half2float(h[(size_t)c7.x * OUT_FEATS + tc]);
        a0 += v0 * __high2float(*reinterpret_cast<__half2*>(&c0.y));
        a1 += v1 * __high2float(*reinterpret_cast<__half2*>(&c1.y));
        a2 += v2 * __high2float(*reinterpret_cast<__half2*>(&c2.y));
        a3 += v3 * __high2float(*reinterpret_cast<__half2*>(&c3.y));
        a0 += v4 * __high2float(*reinterpret_cast<__half2*>(&c4.y));
        a1 += v5 * __high2float(*reinterpret_cast<__half2*>(&c5.y));
        a2 += v6 * __high2float(*reinterpret_cast<__half2*>(&c6.y));
        a3 += v7 * __high2float(*reinterpret_cast<__half2*>(&c7.y));
    }
    for (; j < end; ++j) {
        int2 c = csr[j];
        a0 += __half2float(h[(size_t)c.x * OUT_FEATS + tc]) *
              __high2float(*reinterpret_cast<__half2*>(&c.y));
    }
    float acc = (a0 + a1) + (a2 + a3);

    float v = (t < OUT_FEATS) ? acc + b[t] : -INFINITY;
    float m = v;
#pragma unroll
    for (int off = 32; off; off >>= 1)
        m = fmaxf(m, __shfl_xor(m, off, 64));
    float ex = (t < OUT_FEATS) ? expf(v - m) : 0.f;
    float s = ex;
#pragma unroll
    for (int off = 32; off; off >>= 1)
        s += __shfl_xor(s, off, 64);
    if (t < OUT_FEATS)
        out[n * OUT_FEATS + t] = v - m - logf(s);
}

extern "C" void kernel_launch(void* const* d_in, const int* in_sizes, int n_in,
                              void* d_out, int out_size, void* d_ws, size_t ws_size,
                              hipStream_t stream) {
    const float* features    = (const float*)d_in[0];
    const float* edge_weight = (const float*)d_in[1];
    const int*   src         = (const int*)d_in[2];
    const int*   dst         = (const int*)d_in[3];
    const float* W1          = (const float*)d_in[4];
    const float* b1          = (const float*)d_in[5];
    const float* mu1         = (const float*)d_in[6];
    const float* is1         = (const float*)d_in[7];
    const float* W2          = (const float*)d_in[8];
    const float* b2          = (const float*)d_in[9];
    const float* mu2         = (const float*)d_in[10];
    const float* is2         = (const float*)d_in[11];
    float* out = (float*)d_out;

    // Workspace: csr int2[800k] (6.4MB) | h1 half[3.2M] (6.4MB) | h2 half[2M] (4MB)
    //            | counts | cursor | offsets | blkSums
    int2*   csr    = (int2*)d_ws;
    __half* h1     = (__half*)(csr + N_EDGES);
    __half* h2     = h1 + (size_t)N_NODES * N_HIDDEN;
    int*    counts = (int*)(h2 + (size_t)N_NODES * OUT_FEATS);
    int*    cursor = counts + N_NODES;
    int*    offsets= cursor + N_NODES;
    int*    blkSums= offsets + N_NODES + 1;

    // ---- CSR build ----
    hipMemsetAsync(counts, 0, N_NODES * sizeof(int), stream);
    hist_kernel<<<(N_EDGES + 255) / 256, 256, 0, stream>>>(dst, counts);
    scan_blk_kernel<<<SCAN_NB, 256, 0, stream>>>(counts, offsets, blkSums);
    scan_top_kernel<<<1, 256, 0, stream>>>(blkSums);
    scan_add_kernel<<<SCAN_NB, 256, 0, stream>>>(offsets, blkSums, cursor);
    fill_kernel<<<(N_EDGES + 255) / 256, 256, 0, stream>>>(src, dst, edge_weight,
                                                           mu1, is1, mu2, is2,
                                                           cursor, csr);

    // ---- layer 1 (+ fused layer-2 GEMM) ----
    gemm1_kernel<<<N_NODES / 16, 256, 0, stream>>>(features, W1, h1);
    agg1_gemm2_kernel<<<N_NODES / 4, 256, 0, stream>>>(h1, offsets, csr, b1, W2, h2);

    // ---- layer 2 aggregation + epilogue ----
    agg2_kernel<<<(N_NODES + 3) / 4, 256, 0, stream>>>(h2, offsets, csr, b2, out);
}